// Round 7
// baseline (189.427 us; speedup 1.0000x reference)
//
#include <hip/hip_runtime.h>
#include <hip/hip_cooperative_groups.h>
#include <stdint.h>

namespace cg = cooperative_groups;

// Problem constants: B=8, C=256, K=64, T=1000
constexpr int Bn  = 8;
constexpr int Cn  = 256;
constexpr int Kn  = 64;
constexpr int Tn  = 1000;
constexpr int CH  = 16;    // P1 t-chunk (T padded to 1024)
constexpr int NCH = 64;    // chunks per b
constexpr int TW  = 256;   // P2 t-window
constexpr int NTQ = 4;     // windows per b

constexpr int XT_P = 264;  // xT[t][c] bf16 pitch (16B-aligned rows)
constexpr int MW_P = 20;   // Mw[k][t] f32 pitch
constexpr int XC_P = 264;  // P2 xc[c][t] bf16 pitch

typedef float f32x4 __attribute__((ext_vector_type(4)));
typedef __bf16 bf16x8 __attribute__((ext_vector_type(8)));

__device__ __forceinline__ unsigned short f2bf(float f) {
    unsigned u = __float_as_uint(f);
    return (unsigned short)((u + 0x7FFFu + ((u >> 16) & 1u)) >> 16);  // RNE
}

union BF8 { unsigned short u[8]; bf16x8 v; };

// ---------------------------------------------------------------------------
// Single cooperative kernel: 512 blocks x 256 threads (4 waves), 2 blocks/CU.
// P1: w[b,k,t] (16-t chunk per block) -> w_g bf16 + Sp
// P2: part[b,tq,k,c] = sum_{t in 256-window} w*x  (MFMA)
// P3: reduce + codes*S correction + L2 normalize -> out
// ---------------------------------------------------------------------------
__global__ __launch_bounds__(256) void lde_all(
    const float* __restrict__ x,            // (B, C, T)
    const float* __restrict__ codes,        // (C, K)
    const float* __restrict__ scales,       // (K)
    unsigned short* __restrict__ w_g,       // (B, NCH, K, CH) bf16
    float* __restrict__ Sp,                 // (B, K, NCH)
    float* __restrict__ part,               // (B, NTQ, K, C)
    float* __restrict__ out)                // (B, K, C)
{
    __shared__ __align__(16) unsigned short xT[CH * XT_P];  // P1 [t][c] bf16
    __shared__ __align__(16) unsigned short xc[16 * XC_P];  // P2 [c][t] bf16
    __shared__ float Mw[Kn * MW_P];
    __shared__ float xsqp[64 * 17];
    __shared__ float xsq[CH];
    __shared__ float csqs[Kn];
    __shared__ float spw[4 * 64];
    __shared__ float red[4];
    __shared__ float Ss;

    const int tid  = threadIdx.x;
    const int wave = tid >> 6;
    const int lane = tid & 63;
    const int n    = lane & 15;
    const int q    = lane >> 4;
    const int bid  = blockIdx.x;
    cg::grid_group grid = cg::this_grid();

    // ================= P1: weights =================
    {
        const int b  = bid >> 6;
        const int ch = bid & 63;
        const int t0 = ch * CH;
        const float* xb = x + (size_t)b * Cn * Tn;

        // stage xT (bf16) + xsq partials from the same fp32 registers.
        // thread: tf = tid&3 (t-quad) fixed; c = (tid>>2) + 64r.
        {
            const int tf = tid & 3;
            float sq0 = 0.f, sq1 = 0.f, sq2 = 0.f, sq3 = 0.f;
#pragma unroll
            for (int r = 0; r < 4; ++r) {
                int c = (tid >> 2) + 64 * r;
                int t = t0 + 4 * tf;
                float4 v;
                if (t + 3 < Tn) {
                    v = *(const float4*)(xb + c * Tn + t);
                } else {
                    v.x = (t     < Tn) ? xb[c * Tn + t]     : 0.f;
                    v.y = (t + 1 < Tn) ? xb[c * Tn + t + 1] : 0.f;
                    v.z = (t + 2 < Tn) ? xb[c * Tn + t + 2] : 0.f;
                    v.w = (t + 3 < Tn) ? xb[c * Tn + t + 3] : 0.f;
                }
                xT[(4 * tf + 0) * XT_P + c] = f2bf(v.x);
                xT[(4 * tf + 1) * XT_P + c] = f2bf(v.y);
                xT[(4 * tf + 2) * XT_P + c] = f2bf(v.z);
                xT[(4 * tf + 3) * XT_P + c] = f2bf(v.w);
                sq0 = fmaf(v.x, v.x, sq0);
                sq1 = fmaf(v.y, v.y, sq1);
                sq2 = fmaf(v.z, v.z, sq2);
                sq3 = fmaf(v.w, v.w, sq3);
            }
            float* xp = xsqp + (tid >> 2) * 17 + 4 * tf;
            xp[0] = sq0; xp[1] = sq1; xp[2] = sq2; xp[3] = sq3;
        }
        __syncthreads();

        if (tid < CH) {
            float a = 0.f;
#pragma unroll
            for (int i = 0; i < 64; ++i) a += xsqp[i * 17 + tid];
            xsq[tid] = a;
        }

        // M GEMM: wave = k-tile. A from global fp32 codes (L2-hot, converted
        // in-register); csq[k] computed exactly along the way.
        {
            const int kglob = wave * 16 + n;
            const float* cod = codes + (q * 8) * Kn + kglob;  // codes[c][k]
            float csq_part = 0.f;
            f32x4 acc = {0.f, 0.f, 0.f, 0.f};
#pragma unroll
            for (int c0 = 0; c0 < Cn; c0 += 32) {
                float cf[8];
#pragma unroll
                for (int j = 0; j < 8; ++j) cf[j] = cod[(size_t)(c0 + j) * Kn];
                BF8 aF;
#pragma unroll
                for (int j = 0; j < 8; ++j) {
                    csq_part = fmaf(cf[j], cf[j], csq_part);
                    aF.u[j] = f2bf(cf[j]);
                }
                bf16x8 bF = *(const bf16x8*)(xT + n * XT_P + c0 + q * 8);
                acc = __builtin_amdgcn_mfma_f32_16x16x32_bf16(aF.v, bF, acc, 0, 0, 0);
            }
            csq_part += __shfl_xor(csq_part, 16, 64);
            csq_part += __shfl_xor(csq_part, 32, 64);
            if (q == 0) csqs[kglob] = csq_part;
#pragma unroll
            for (int r = 0; r < 4; ++r)
                Mw[(wave * 16 + q * 4 + r) * MW_P + n] = acc[r];  // col n -> t
        }
        __syncthreads();

        // softmax over k (lane = k); wave handles t = wave*4..+3
        {
            const float sc = scales[lane];
            const float cq = csqs[lane];
            unsigned short wh[4];
            float sp = 0.f;
#pragma unroll
            for (int j = 0; j < 4; ++j) {
                int t = wave * 4 + j;
                float m     = Mw[lane * MW_P + t];
                float logit = -sc * (xsq[t] - 2.f * m + cq);
                float mx = logit;
#pragma unroll
                for (int off = 32; off >= 1; off >>= 1)
                    mx = fmaxf(mx, __shfl_xor(mx, off, 64));
                float e = __expf(logit - mx);
                float s = e;
#pragma unroll
                for (int off = 32; off >= 1; off >>= 1)
                    s += __shfl_xor(s, off, 64);
                float wv = e / s;
                if (t0 + t >= Tn) wv = 0.f;
                sp += wv;
                wh[j] = f2bf(wv);
            }
            *(ushort4*)(w_g + ((size_t)(b * NCH + ch) * Kn + lane) * CH + wave * 4) =
                make_ushort4(wh[0], wh[1], wh[2], wh[3]);
            spw[wave * 64 + lane] = sp;
        }
        __syncthreads();
        if (wave == 0) {
            float s4 = spw[lane] + spw[64 + lane] + spw[128 + lane] + spw[192 + lane];
            Sp[((size_t)b * Kn + lane) * NCH + ch] = s4;
        }
    }
    grid.sync();

    // ================= P2: pool =================
    {
        const int b   = bid >> 6;
        const int ct  = (bid >> 2) & 15;
        const int tq  = bid & 3;
        const int c0  = ct * 16;
        const int tw0 = tq * TW;
        const float* xb = x + (size_t)(b * Cn + c0) * Tn;

#pragma unroll
        for (int r = 0; r < 4; ++r) {
            int idx = r * 256 + tid;
            int cl = idx >> 6, tf = idx & 63;
            int t = tw0 + 4 * tf;
            float4 v;
            if (t + 3 < Tn) {
                v = *(const float4*)(xb + cl * Tn + t);
            } else {
                v.x = (t     < Tn) ? xb[cl * Tn + t]     : 0.f;
                v.y = (t + 1 < Tn) ? xb[cl * Tn + t + 1] : 0.f;
                v.z = (t + 2 < Tn) ? xb[cl * Tn + t + 2] : 0.f;
                v.w = (t + 3 < Tn) ? xb[cl * Tn + t + 3] : 0.f;
            }
            *(ushort4*)(xc + cl * XC_P + 4 * tf) =
                make_ushort4(f2bf(v.x), f2bf(v.y), f2bf(v.z), f2bf(v.w));
        }
        __syncthreads();

        f32x4 acc = {0.f, 0.f, 0.f, 0.f};
#pragma unroll
        for (int s = 0; s < 8; ++s) {
            int tg  = tw0 + s * 32 + q * 8;
            int chh = tg >> 4;
            int tl  = tg & 15;
            bf16x8 aF = *(const bf16x8*)(w_g + ((size_t)(b * NCH + chh) * Kn + wave * 16 + n) * CH + tl);
            bf16x8 bF = *(const bf16x8*)(xc + n * XC_P + s * 32 + q * 8);
            acc = __builtin_amdgcn_mfma_f32_16x16x32_bf16(aF, bF, acc, 0, 0, 0);
        }
        float* pb = part + ((size_t)(b * NTQ + tq) * Kn + wave * 16 + q * 4) * Cn + c0 + n;
#pragma unroll
        for (int r = 0; r < 4; ++r)
            pb[(size_t)r * Cn] = acc[r];
    }
    grid.sync();

    // ================= P3: finish =================
    {
        const int b = bid >> 6;
        const int k = bid & 63;

        if (wave == 0) {
            float s = Sp[((size_t)b * Kn + k) * NCH + lane];  // 256B coalesced
#pragma unroll
            for (int off = 32; off >= 1; off >>= 1) s += __shfl_xor(s, off, 64);
            if (lane == 0) Ss = s;
        }
        __syncthreads();
        const float S = Ss;

        const int c = tid;
        const float* pb = part + (size_t)b * NTQ * Kn * Cn + k * Cn + c;
        float val = pb[0] + pb[(size_t)Kn * Cn] + pb[(size_t)2 * Kn * Cn] + pb[(size_t)3 * Kn * Cn];

        float e = (val - codes[c * Kn + k] * S) * (1.0f / (float)Tn);

        float qq = e * e;
#pragma unroll
        for (int off = 32; off >= 1; off >>= 1) qq += __shfl_xor(qq, off, 64);
        if (lane == 0) red[wave] = qq;
        __syncthreads();
        float nn = sqrtf(red[0] + red[1] + red[2] + red[3]);

        out[((size_t)b * Kn + k) * Cn + c] = e / fmaxf(nn, 1e-12f);
    }
}

extern "C" void kernel_launch(void* const* d_in, const int* in_sizes, int n_in,
                              void* d_out, int out_size, void* d_ws, size_t ws_size,
                              hipStream_t stream) {
    const float* x      = (const float*)d_in[0];   // (B, C, T) f32
    const float* codes  = (const float*)d_in[1];   // (C, K)    f32
    const float* scales = (const float*)d_in[2];   // (K)       f32
    float* out = (float*)d_out;                    // (B, K, C) f32

    char* ws = (char*)d_ws;
    float*          part = (float*)ws;                          // 2 MB
    unsigned short* w_g  = (unsigned short*)(ws + (2u << 20));  // 1 MB
    float*          Sp   = (float*)(ws + (3u << 20));           // 128 KB

    void* args[] = { (void*)&x, (void*)&codes, (void*)&scales,
                     (void*)&w_g, (void*)&Sp, (void*)&part, (void*)&out };
    hipLaunchCooperativeKernel((const void*)lde_all, dim3(Bn * NCH), dim3(256),
                               args, 0, stream);
}

// Round 8
// 75.728 us; speedup vs baseline: 2.5014x; 2.5014x over previous
//
#include <hip/hip_runtime.h>
#include <stdint.h>

// Problem constants: B=8, C=256, K=64, T=1000
constexpr int Bn  = 8;
constexpr int Cn  = 256;
constexpr int Kn  = 64;
constexpr int Tn  = 1000;
constexpr int CH  = 16;    // K1 t-chunk (T padded to 1024)
constexpr int NCH = 64;    // chunks per b
constexpr int TW  = 256;   // K2 t-window
constexpr int NTQ = 4;     // windows per b

constexpr int XT_P = 264;  // xT[t][c] bf16 pitch (16B-aligned rows)
constexpr int MW_P = 20;   // Mw[k][t] f32 pitch
constexpr int XC_P = 264;  // K2 xc[c][t] bf16 pitch

typedef float f32x4 __attribute__((ext_vector_type(4)));
typedef __bf16 bf16x8 __attribute__((ext_vector_type(8)));

__device__ __forceinline__ unsigned short f2bf(float f) {
    unsigned u = __float_as_uint(f);
    return (unsigned short)((u + 0x7FFFu + ((u >> 16) & 1u)) >> 16);  // RNE
}

union BF8 { unsigned short u[8]; bf16x8 v; };

// ---------------------------------------------------------------------------
// K1 weights (prep folded in): grid (b x 64 chunks of 16t) = 512 blocks,
// 256 thr (4 waves, 2 waves/SIMD at 2 blocks/CU).
//   A-operand: codes fp32 read strided in fragment order, converted to bf16
//              in-register; csq[k] accumulated exactly in fp32 on the way.
//   B-operand: x staged to LDS bf16 (xT), xsq from the same fp32 registers.
//   M[k,t] via mfma 16x16x32; softmax fp32; out w_g bf16 + Sp f32.
// ---------------------------------------------------------------------------
__global__ __launch_bounds__(256) void lde_w(
    const float* __restrict__ x,            // (B, C, T)
    const float* __restrict__ codes,        // (C, K)
    const float* __restrict__ scales,       // (K)
    unsigned short* __restrict__ w_g,       // (B, NCH, K, CH) bf16
    float* __restrict__ Sp)                 // (B, K, NCH)
{
    __shared__ __align__(16) unsigned short xT[CH * XT_P];  // [t][c] bf16
    __shared__ float Mw[Kn * MW_P];                         // [k][t]
    __shared__ float xsqp[64 * 17];
    __shared__ float xsq[CH];
    __shared__ float csqs[Kn];
    __shared__ float spw[4 * 64];

    const int tid  = threadIdx.x;
    const int wave = tid >> 6;
    const int lane = tid & 63;
    const int n    = lane & 15;
    const int q    = lane >> 4;
    const int b    = blockIdx.x >> 6;
    const int ch   = blockIdx.x & 63;
    const int t0   = ch * CH;
    const float* xb = x + (size_t)b * Cn * Tn;

    // --- stage xT (bf16) + xsq partials from the same fp32 registers ---
    // thread: tf = tid&3 (t-quad) fixed; c = (tid>>2) + 64r.
    {
        const int tf = tid & 3;
        float sq0 = 0.f, sq1 = 0.f, sq2 = 0.f, sq3 = 0.f;
#pragma unroll
        for (int r = 0; r < 4; ++r) {
            int c = (tid >> 2) + 64 * r;
            int t = t0 + 4 * tf;
            float4 v;
            if (t + 3 < Tn) {
                v = *(const float4*)(xb + c * Tn + t);
            } else {
                v.x = (t     < Tn) ? xb[c * Tn + t]     : 0.f;
                v.y = (t + 1 < Tn) ? xb[c * Tn + t + 1] : 0.f;
                v.z = (t + 2 < Tn) ? xb[c * Tn + t + 2] : 0.f;
                v.w = (t + 3 < Tn) ? xb[c * Tn + t + 3] : 0.f;
            }
            xT[(4 * tf + 0) * XT_P + c] = f2bf(v.x);
            xT[(4 * tf + 1) * XT_P + c] = f2bf(v.y);
            xT[(4 * tf + 2) * XT_P + c] = f2bf(v.z);
            xT[(4 * tf + 3) * XT_P + c] = f2bf(v.w);
            sq0 = fmaf(v.x, v.x, sq0);
            sq1 = fmaf(v.y, v.y, sq1);
            sq2 = fmaf(v.z, v.z, sq2);
            sq3 = fmaf(v.w, v.w, sq3);
        }
        float* xp = xsqp + (tid >> 2) * 17 + 4 * tf;
        xp[0] = sq0; xp[1] = sq1; xp[2] = sq2; xp[3] = sq3;
    }
    __syncthreads();

    if (tid < CH) {
        float a = 0.f;
#pragma unroll
        for (int i = 0; i < 64; ++i) a += xsqp[i * 17 + tid];
        xsq[tid] = a;
    }

    // --- M GEMM: wave = k-tile. A from global fp32 codes, converted bf16;
    //     csq[k] exact fp32 along the way. B from LDS xT. ---
    {
        const int kglob = wave * 16 + n;
        const float* cod = codes + (q * 8) * Kn + kglob;  // codes[c][k]
        float csq_part = 0.f;
        f32x4 acc = {0.f, 0.f, 0.f, 0.f};
#pragma unroll
        for (int c0 = 0; c0 < Cn; c0 += 32) {
            float cf[8];
#pragma unroll
            for (int j = 0; j < 8; ++j) cf[j] = cod[(size_t)(c0 + j) * Kn];
            BF8 aF;
#pragma unroll
            for (int j = 0; j < 8; ++j) {
                csq_part = fmaf(cf[j], cf[j], csq_part);
                aF.u[j] = f2bf(cf[j]);
            }
            bf16x8 bF = *(const bf16x8*)(xT + n * XT_P + c0 + q * 8);
            acc = __builtin_amdgcn_mfma_f32_16x16x32_bf16(aF.v, bF, acc, 0, 0, 0);
        }
        csq_part += __shfl_xor(csq_part, 16, 64);
        csq_part += __shfl_xor(csq_part, 32, 64);
        if (q == 0) csqs[kglob] = csq_part;
#pragma unroll
        for (int r = 0; r < 4; ++r)
            Mw[(wave * 16 + q * 4 + r) * MW_P + n] = acc[r];  // col n -> t
    }
    __syncthreads();

    // --- softmax over k (lane = k); wave handles t = wave*4..+3 ---
    {
        const float sc = scales[lane];
        const float cq = csqs[lane];
        unsigned short wh[4];
        float sp = 0.f;
#pragma unroll
        for (int j = 0; j < 4; ++j) {
            int t = wave * 4 + j;
            float m     = Mw[lane * MW_P + t];
            float logit = -sc * (xsq[t] - 2.f * m + cq);
            float mx = logit;
#pragma unroll
            for (int off = 32; off >= 1; off >>= 1)
                mx = fmaxf(mx, __shfl_xor(mx, off, 64));
            float e = __expf(logit - mx);
            float s = e;
#pragma unroll
            for (int off = 32; off >= 1; off >>= 1)
                s += __shfl_xor(s, off, 64);
            float wv = e / s;
            if (t0 + t >= Tn) wv = 0.f;
            sp += wv;
            wh[j] = f2bf(wv);
        }
        *(ushort4*)(w_g + ((size_t)(b * NCH + ch) * Kn + lane) * CH + wave * 4) =
            make_ushort4(wh[0], wh[1], wh[2], wh[3]);
        spw[wave * 64 + lane] = sp;
    }
    __syncthreads();
    if (wave == 0) {
        float s4 = spw[lane] + spw[64 + lane] + spw[128 + lane] + spw[192 + lane];
        Sp[((size_t)b * Kn + lane) * NCH + ch] = s4;
    }
}

// ---------------------------------------------------------------------------
// K2 pool: grid (b x 16 c-tiles x 4 t-windows of 256) = 512 blocks, 4 waves.
//   part[b,tq,k,c] = sum_{t in window} w[k,t] * x[c,t]   (8 mfma / wave)
// ---------------------------------------------------------------------------
__global__ __launch_bounds__(256) void lde_pool(
    const float* __restrict__ x,            // (B, C, T)
    const unsigned short* __restrict__ w_g, // (B, NCH, K, CH) bf16
    float* __restrict__ part)               // (B, NTQ, K, C)
{
    __shared__ __align__(16) unsigned short xc[16 * XC_P];  // [c-local][t-local]

    const int tid  = threadIdx.x;
    const int wave = tid >> 6;            // k-tile
    const int lane = tid & 63;
    const int n    = lane & 15;
    const int q    = lane >> 4;
    const int bid  = blockIdx.x;
    const int b    = bid >> 6;
    const int ct   = (bid >> 2) & 15;
    const int tq   = bid & 3;
    const int c0   = ct * 16;
    const int tw0  = tq * TW;
    const float* xb = x + (size_t)(b * Cn + c0) * Tn;

#pragma unroll
    for (int r = 0; r < 4; ++r) {
        int idx = r * 256 + tid;
        int cl = idx >> 6, tf = idx & 63;
        int t = tw0 + 4 * tf;
        float4 v;
        if (t + 3 < Tn) {
            v = *(const float4*)(xb + cl * Tn + t);
        } else {
            v.x = (t     < Tn) ? xb[cl * Tn + t]     : 0.f;
            v.y = (t + 1 < Tn) ? xb[cl * Tn + t + 1] : 0.f;
            v.z = (t + 2 < Tn) ? xb[cl * Tn + t + 2] : 0.f;
            v.w = (t + 3 < Tn) ? xb[cl * Tn + t + 3] : 0.f;
        }
        *(ushort4*)(xc + cl * XC_P + 4 * tf) =
            make_ushort4(f2bf(v.x), f2bf(v.y), f2bf(v.z), f2bf(v.w));
    }
    __syncthreads();

    f32x4 acc = {0.f, 0.f, 0.f, 0.f};
#pragma unroll
    for (int s = 0; s < 8; ++s) {
        int tg  = tw0 + s * 32 + q * 8;       // global t of this frag
        int chh = tg >> 4;                    // chunk in w_g
        int tl  = tg & 15;                    // 0 or 8
        bf16x8 aF = *(const bf16x8*)(w_g + ((size_t)(b * NCH + chh) * Kn + wave * 16 + n) * CH + tl);
        bf16x8 bF = *(const bf16x8*)(xc + n * XC_P + s * 32 + q * 8);
        acc = __builtin_amdgcn_mfma_f32_16x16x32_bf16(aF, bF, acc, 0, 0, 0);
    }
    // D: col n -> c, row q*4+r -> k
    float* pb = part + ((size_t)(b * NTQ + tq) * Kn + wave * 16 + q * 4) * Cn + c0 + n;
#pragma unroll
    for (int r = 0; r < 4; ++r)
        pb[(size_t)r * Cn] = acc[r];
}

// ---------------------------------------------------------------------------
// K3 finish: block per (b,k), 256 thr = c.
// ---------------------------------------------------------------------------
__global__ __launch_bounds__(256) void lde_fin(
    const float* __restrict__ part,    // (B, NTQ, K, C)
    const float* __restrict__ Sp,      // (B, K, NCH)
    const float* __restrict__ codes,   // (C, K)
    float* __restrict__ out)           // (B, K, C)
{
    const int b    = blockIdx.x >> 6;
    const int k    = blockIdx.x & 63;
    const int tid  = threadIdx.x;
    const int lane = tid & 63;
    const int wave = tid >> 6;

    __shared__ float red[4];
    __shared__ float Ss;

    if (wave == 0) {
        float s = Sp[((size_t)b * Kn + k) * NCH + lane];   // 256B coalesced
#pragma unroll
        for (int off = 32; off >= 1; off >>= 1) s += __shfl_xor(s, off, 64);
        if (lane == 0) Ss = s;
    }
    __syncthreads();
    const float S = Ss;

    const int c = tid;
    const float* pb = part + (size_t)b * NTQ * Kn * Cn + k * Cn + c;
    float val = pb[0] + pb[(size_t)Kn * Cn] + pb[(size_t)2 * Kn * Cn] + pb[(size_t)3 * Kn * Cn];

    float e = (val - codes[c * Kn + k] * S) * (1.0f / (float)Tn);

    float qq = e * e;
#pragma unroll
    for (int off = 32; off >= 1; off >>= 1) qq += __shfl_xor(qq, off, 64);
    if (lane == 0) red[wave] = qq;
    __syncthreads();
    float nn = sqrtf(red[0] + red[1] + red[2] + red[3]);

    out[((size_t)b * Kn + k) * Cn + c] = e / fmaxf(nn, 1e-12f);
}

extern "C" void kernel_launch(void* const* d_in, const int* in_sizes, int n_in,
                              void* d_out, int out_size, void* d_ws, size_t ws_size,
                              hipStream_t stream) {
    const float* x      = (const float*)d_in[0];   // (B, C, T) f32
    const float* codes  = (const float*)d_in[1];   // (C, K)    f32
    const float* scales = (const float*)d_in[2];   // (K)       f32
    float* out = (float*)d_out;                    // (B, K, C) f32

    char* ws = (char*)d_ws;
    float*          part = (float*)ws;                          // 2 MB
    unsigned short* w_g  = (unsigned short*)(ws + (2u << 20));  // 1 MB
    float*          Sp   = (float*)(ws + (3u << 20));           // 128 KB

    lde_w   <<<Bn * NCH,      256, 0, stream>>>(x, codes, scales, w_g, Sp);
    lde_pool<<<Bn * 16 * NTQ, 256, 0, stream>>>(x, w_g, part);
    lde_fin <<<Bn * Kn,       256, 0, stream>>>(part, Sp, codes, out);
}